// Round 19
// baseline (239.933 us; speedup 1.0000x reference)
//
#include <hip/hip_runtime.h>

#define S_LEN 2048
#define DIM 2048
#define NH 16
#define HD 128
#define WIN 512
#define QKVD (3 * DIM)  // 6144

typedef unsigned short u16;
typedef unsigned int u32;
typedef __bf16 bf16x8 __attribute__((ext_vector_type(8)));
typedef float f32x4 __attribute__((ext_vector_type(4)));

__device__ __forceinline__ u16 f2bf(float f) {
  unsigned u = __builtin_bit_cast(unsigned, f);
  u += 0x7FFFu + ((u >> 16) & 1u);
  return (u16)(u >> 16);
}
__device__ __forceinline__ float bf2f(u16 b) {
  return __builtin_bit_cast(float, (unsigned)b << 16);
}
__device__ __forceinline__ void async16(const void* g, void* l) {
  __builtin_amdgcn_global_load_lds((__attribute__((address_space(1))) void*)g,
                                   (__attribute__((address_space(3))) void*)l,
                                   16, 0, 0);
}
#define WAITV(N) asm volatile("s_waitcnt vmcnt(" #N ")" ::: "memory")

// ---- merged fp32->bf16 convert (3 arrays) + RoPE table, one launch --------
__global__ __launch_bounds__(256) void cvt3tab_kernel(
    const float* __restrict__ a, u16* __restrict__ oa, int na,
    const float* __restrict__ b, u16* __restrict__ ob, int nb,
    const float* __restrict__ c, u16* __restrict__ oc, int nc,
    float* __restrict__ cosT, float* __restrict__ sinT, int nCvt) {
  if ((int)blockIdx.x >= nCvt) {
    int idx = ((int)blockIdx.x - nCvt) * 256 + threadIdx.x;  // S*64 entries
    int s = idx >> 6, j = idx & 63;
    double freq = exp((double)j * -0.14391156831212787);  // -ln(10000)/64
    double ang = (double)s * freq;
    cosT[idx] = (float)cos(ang);
    sinT[idx] = (float)sin(ang);
    return;
  }
  int i = (blockIdx.x * 256 + threadIdx.x) * 4;
  const float* src;
  u16* dst;
  if (i < na) { src = a + i; dst = oa + i; }
  else if (i < na + nb) { src = b + (i - na); dst = ob + (i - na); }
  else if (i < na + nb + nc) { src = c + (i - na - nb); dst = oc + (i - na - nb); }
  else return;
  float4 v = *(const float4*)src;
  ushort4 o;
  o.x = f2bf(v.x); o.y = f2bf(v.y); o.z = f2bf(v.z); o.w = f2bf(v.w);
  *(ushort4*)dst = o;
}

// ============ 128xBN 4-phase/K-tile GEMM: C = A * B^T ============
// BM=128, BN in {384, 256}; 512 thr (8 waves, 2M x 4N), BK=64, dbuf LDS.
// r8-proven stagger: ph1->B0(t+1), ph2->B1(t+1), ph3->A1(t+1), ph4->A0(t+2).
// FIFO waits per BN: 384 [3,3,1,1] -> 5/7/-/5 ; 256 [2,2,1,1] -> 4/5/-/4.
template <int BN, typename TO>
__global__ __launch_bounds__(512, 2) void gemm8(const u16* __restrict__ A,
                                                const u16* __restrict__ B,
                                                TO* __restrict__ C,
                                                int M, int N, int K) {
  constexpr int ABY = 128 * 128;
  constexpr int BBY = BN * 128;
  constexpr int BLO = BN / 128;
  __shared__ __align__(16) char Al[2 * ABY];
  __shared__ __align__(16) char Bl[2 * BBY];

  const int tiles_n = N / BN;
  const int tiles_m = M >> 7;
  int m0, n0;
  if constexpr (BN == 384) {       // n-pinned (QKV, r15-proven)
    const int npx = tiles_n >> 3;
    const int xcd = (int)blockIdx.x & 7;
    const int idx = (int)blockIdx.x >> 3;
    m0 = (idx % tiles_m) << 7;
    n0 = (xcd * npx + idx / tiles_m) * BN;
  } else {                         // m-chunked (out-proj, r13-proven)
    const int nwg = gridDim.x;
    const int wg = ((int)blockIdx.x & 7) * (nwg >> 3) + ((int)blockIdx.x >> 3);
    m0 = (wg / tiles_n) << 7;
    n0 = (wg % tiles_n) * BN;
  }
  const int t = threadIdx.x;
  const int l = t & 63, w = t >> 6;
  const int wr = w >> 2, wc = w & 3;
  const int l16 = l & 15, lg = l >> 4;
  const u16* Asrc = A + (size_t)m0 * K;
  const u16* Bsrc = B + (size_t)n0 * K;

  auto stA = [&](int kcol, int half, int b) {
    int rih = t >> 3, ch = t & 7;
    int row = half * 64 + rih;
    async16(Asrc + (size_t)row * K + kcol + ((ch ^ (row & 7)) << 3),
            Al + b * ABY + row * 128 + ch * 16);
  };
  auto stB = [&](int kcol, int half, int b) {
#pragma unroll
    for (int j = 0; j < BLO; ++j) {
      int c = t + j * 512;
      int rih = c >> 3, ch = c & 7;
      int row = half * (BN / 2) + rih;
      async16(Bsrc + (size_t)row * K + kcol + ((ch ^ (row & 7)) << 3),
              Bl + b * BBY + row * 128 + ch * 16);
    }
  };

  f32x4 acc[4][2 * BLO] = {};
  bf16x8 af[2][2];
  bf16x8 bfr[2][BLO][2];

  auto rdA = [&](int b, int mh) {
#pragma unroll
    for (int m = 0; m < 2; ++m)
#pragma unroll
      for (int ks = 0; ks < 2; ++ks) {
        int row = wr * 64 + mh * 32 + m * 16 + l16;
        int ch = ks * 4 + lg;
        af[m][ks] = *(const bf16x8*)(Al + b * ABY + row * 128 + ((ch ^ (row & 7)) << 4));
      }
  };
  auto rdB = [&](int b, int nh) {
#pragma unroll
    for (int n = 0; n < BLO; ++n)
#pragma unroll
      for (int ks = 0; ks < 2; ++ks) {
        int row = wc * (BN / 4) + nh * (BN / 8) + n * 16 + l16;
        int ch = ks * 4 + lg;
        bfr[nh][n][ks] = *(const bf16x8*)(Bl + b * BBY + row * 128 + ((ch ^ (row & 7)) << 4));
      }
  };
  auto mm = [&](int mh, int nh) {
#pragma unroll
    for (int m = 0; m < 2; ++m)
#pragma unroll
      for (int n = 0; n < BLO; ++n)
#pragma unroll
        for (int ks = 0; ks < 2; ++ks)
          acc[mh * 2 + m][nh * BLO + n] = __builtin_amdgcn_mfma_f32_16x16x32_bf16(
              af[m][ks], bfr[nh][n][ks], acc[mh * 2 + m][nh * BLO + n], 0, 0, 0);
  };

  const int NT = K >> 6;
  stA(0, 0, 0); stB(0, 0, 0); stB(0, 1, 0); stA(0, 1, 0); stA(64, 0, 1);
  if constexpr (BN == 384) WAITV(5); else WAITV(4);
  __builtin_amdgcn_s_barrier();

  for (int kt = 0; kt < NT; ++kt) {
    const int b = kt & 1, nb = b ^ 1;
    const int k1 = ((kt + 1 < NT) ? kt + 1 : kt) << 6;
    const int k2 = ((kt + 2 < NT) ? kt + 2 : kt) << 6;
    rdA(b, 0); rdB(b, 0);
    stB(k1, 0, nb);
    __builtin_amdgcn_s_barrier();
    __builtin_amdgcn_s_setprio(1); mm(0, 0); __builtin_amdgcn_s_setprio(0);
    if constexpr (BN == 384) WAITV(5); else WAITV(4);  // drain B1(t)
    __builtin_amdgcn_s_barrier();
    rdB(b, 1);
    stB(k1, 1, nb);
    __builtin_amdgcn_s_barrier();
    __builtin_amdgcn_s_setprio(1); mm(0, 1); __builtin_amdgcn_s_setprio(0);
    if constexpr (BN == 384) WAITV(7); else WAITV(5);  // drain A1(t)
    __builtin_amdgcn_s_barrier();
    rdA(b, 1);
    stA(k1, 1, nb);
    __builtin_amdgcn_s_barrier();
    __builtin_amdgcn_s_setprio(1); mm(1, 0); __builtin_amdgcn_s_setprio(0);
    __builtin_amdgcn_s_barrier();
    stA(k2, 0, b);
    __builtin_amdgcn_s_barrier();
    __builtin_amdgcn_s_setprio(1); mm(1, 1); __builtin_amdgcn_s_setprio(0);
    if constexpr (BN == 384) WAITV(5); else WAITV(4);  // drain A0/B0(t+1)
    __builtin_amdgcn_s_barrier();
  }

  const int rb = m0 + wr * 64 + lg * 4;
  const int cb = n0 + wc * (BN / 4) + l16;
#pragma unroll
  for (int mi = 0; mi < 4; ++mi)
#pragma unroll
    for (int ni = 0; ni < 2 * BLO; ++ni)
#pragma unroll
      for (int r = 0; r < 4; ++r) {
        float v = acc[mi][ni][r];
        size_t idx2 = (size_t)(rb + mi * 16 + r) * N + cb + ni * 16;
        if constexpr (sizeof(TO) == 2) C[idx2] = f2bf(v);
        else C[idx2] = v;
      }
}

// -------- RoPE in-place on K ONLY (Q is rope'd in-register inside attn) -----
__global__ __launch_bounds__(256) void ropek_kernel(u16* __restrict__ qkv,
                                                    const float* __restrict__ cosT,
                                                    const float* __restrict__ sinT) {
  const int row = blockIdx.x * 2 + (threadIdx.x >> 7);  // b*S + s
  const int s = row & (S_LEN - 1);
  const int slot = threadIdx.x & 127;
  const int h = slot >> 3;
  const int c = slot & 7;
  u16* p = qkv + (size_t)row * QKVD + DIM + h * HD + c * 8;  // K part
  const float* cp = cosT + (s << 6) + c * 8;
  const float* sp = sinT + (s << 6) + c * 8;
  const float4 c0 = *(const float4*)cp, c1 = *(const float4*)(cp + 4);
  const float4 s0 = *(const float4*)sp, s1 = *(const float4*)(sp + 4);
  float cs[8] = {c0.x, c0.y, c0.z, c0.w, c1.x, c1.y, c1.z, c1.w};
  float sn[8] = {s0.x, s0.y, s0.z, s0.w, s1.x, s1.y, s1.z, s1.w};
  uint4 lo = *(const uint4*)p;
  uint4 hi = *(const uint4*)(p + 64);
  unsigned lw[4] = {lo.x, lo.y, lo.z, lo.w};
  unsigned hw[4] = {hi.x, hi.y, hi.z, hi.w};
  unsigned ol[4], oh[4];
#pragma unroll
  for (int j = 0; j < 4; ++j) {
    float x1a = bf2f((u16)(lw[j] & 0xffffu)), x1b = bf2f((u16)(lw[j] >> 16));
    float x2a = bf2f((u16)(hw[j] & 0xffffu)), x2b = bf2f((u16)(hw[j] >> 16));
    float ca = cs[j * 2], cb = cs[j * 2 + 1];
    float sa = sn[j * 2], sb = sn[j * 2 + 1];
    ol[j] = (u32)f2bf(x1a * ca - x2a * sa) | ((u32)f2bf(x1b * cb - x2b * sb) << 16);
    oh[j] = (u32)f2bf(x2a * ca + x1a * sa) | ((u32)f2bf(x2b * cb + x1b * sb) << 16);
  }
  *(uint4*)p = (uint4){ol[0], ol[1], ol[2], ol[3]};
  *(uint4*)(p + 64) = (uint4){oh[0], oh[1], oh[2], oh[3]};
}

// -------- sliding-window flash attention: KVBLK=128 (per-tile overhead /2) --
// grid = (B*H) * (S/128) = 512 blocks; 8 waves x 16 q-rows; ~5 tiles/block.
// Ks dbuf 2x32KB; V prefetch 4x uint4 (kv and kv+64); P = [16][128] per wave.
__global__ __launch_bounds__(512, 1) void attn_kernel(const u16* __restrict__ qkv,
                                                      u16* __restrict__ attnO,
                                                      const float* __restrict__ cosT,
                                                      const float* __restrict__ sinT) {
  const int nwg = gridDim.x;  // 512
  const int wg = ((int)blockIdx.x & 7) * (nwg >> 3) + ((int)blockIdx.x >> 3);
  const int qt = wg & 15;
  const int bh = wg >> 4;
  const int q0 = qt << 7;
  const int b = bh >> 4, h = bh & 15;
  const u16* Qp = qkv + (size_t)b * S_LEN * QKVD + h * HD;
  const u16* Kp = Qp + DIM;
  const u16* Vp = Qp + 2 * DIM;
  __shared__ __align__(16) char Ks[2][128 * 256];  // dbuf XOR-swizzled K (64KB)
  __shared__ __align__(16) u16 Vt[128][136];       // transposed V, padded (34.8KB)
  __shared__ __align__(16) u32 Ps[8][16 * 68];     // per-wave P[q][kv128] (34.8KB)
  const int t = threadIdx.x;
  const int w = t >> 6, l = t & 63;
  const int l16 = l & 15, lg = l >> 4;
  const int q0w = q0 + w * 16;
  const bf16x8 ones = __builtin_bit_cast(bf16x8,
      (uint4){0x3F803F80u, 0x3F803F80u, 0x3F803F80u, 0x3F803F80u});
  bf16x8 qf[4];
  {
    const u16* qrow = Qp + (size_t)(q0w + l16) * QKVD;
#pragma unroll
    for (int ks = 0; ks < 4; ++ks) qf[ks] = *(const bf16x8*)(qrow + ks * 32 + lg * 8);
    // in-register RoPE on Q
    const int srow = q0w + l16;
    const float* cbase = cosT + (srow << 6) + lg * 8;
    const float* sbase = sinT + (srow << 6) + lg * 8;
#pragma unroll
    for (int ks = 0; ks < 2; ++ks) {
      const float4 ca = *(const float4*)(cbase + ks * 32);
      const float4 cb2 = *(const float4*)(cbase + ks * 32 + 4);
      const float4 sa = *(const float4*)(sbase + ks * 32);
      const float4 sb2 = *(const float4*)(sbase + ks * 32 + 4);
      const float cs[8] = {ca.x, ca.y, ca.z, ca.w, cb2.x, cb2.y, cb2.z, cb2.w};
      const float sn[8] = {sa.x, sa.y, sa.z, sa.w, sb2.x, sb2.y, sb2.z, sb2.w};
      const uint4 lv = __builtin_bit_cast(uint4, qf[ks]);
      const uint4 hv = __builtin_bit_cast(uint4, qf[ks + 2]);
      const unsigned li[4] = {lv.x, lv.y, lv.z, lv.w};
      const unsigned hi2[4] = {hv.x, hv.y, hv.z, hv.w};
      unsigned lw[4], hw[4];
#pragma unroll
      for (int p2 = 0; p2 < 4; ++p2) {
        float f1a = bf2f((u16)(li[p2] & 0xffffu)), f1b = bf2f((u16)(li[p2] >> 16));
        float f2a = bf2f((u16)(hi2[p2] & 0xffffu)), f2b = bf2f((u16)(hi2[p2] >> 16));
        lw[p2] = (u32)f2bf(f1a * cs[p2 * 2] - f2a * sn[p2 * 2]) |
                 ((u32)f2bf(f1b * cs[p2 * 2 + 1] - f2b * sn[p2 * 2 + 1]) << 16);
        hw[p2] = (u32)f2bf(f2a * cs[p2 * 2] + f1a * sn[p2 * 2]) |
                 ((u32)f2bf(f2b * cs[p2 * 2 + 1] + f1b * sn[p2 * 2 + 1]) << 16);
      }
      qf[ks] = __builtin_bit_cast(bf16x8, (uint4){lw[0], lw[1], lw[2], lw[3]});
      qf[ks + 2] = __builtin_bit_cast(bf16x8, (uint4){hw[0], hw[1], hw[2], hw[3]});
    }
  }
  f32x4 oacc[8] = {};
  f32x4 ldacc = {};
  const int lo = max(0, (q0 - (WIN - 1)) >> 7);
  const int hi = qt;  // (q0+127)>>7
  const int lo_w = max(0, (q0w - (WIN - 1)) >> 7);
  const int hi_w = (q0w + 15) >> 7;
  const float SC2 = 0.12751744654f;  // log2(e)/sqrt(128)
  const int qi = q0w + l16;
  const int dc = t & 15, pr_ = t >> 4;  // V-stage: d-chunk, kv-pair (0..31)

  auto loadV = [&](int kv0, uint4& va, uint4& vb, uint4& vc, uint4& vd) {
    va = *(const uint4*)(Vp + (size_t)(kv0 + pr_ * 2) * QKVD + dc * 8);
    vb = *(const uint4*)(Vp + (size_t)(kv0 + pr_ * 2 + 1) * QKVD + dc * 8);
    vc = *(const uint4*)(Vp + (size_t)(kv0 + 64 + pr_ * 2) * QKVD + dc * 8);
    vd = *(const uint4*)(Vp + (size_t)(kv0 + 64 + pr_ * 2 + 1) * QKVD + dc * 8);
  };
  auto issueK = [&](int kv0, int buf) {
#pragma unroll
    for (int i = 0; i < 4; ++i) {
      int c = t + (i << 9);
      int row = c >> 4, ch = c & 15;
      int sch = ch ^ (row & 7);
      async16(Kp + (size_t)(kv0 + row) * QKVD + sch * 8, Ks[buf] + c * 16);
    }
  };

  uint4 va, vb, vc, vd, va2, vb2, vc2, vd2;
  loadV(lo << 7, va, vb, vc, vd);
  __builtin_amdgcn_sched_barrier(0);
  issueK(lo << 7, 0);
  __builtin_amdgcn_sched_barrier(0);

  for (int kt = lo; kt <= hi; ++kt) {
    const int buf = (kt - lo) & 1;
    const int kv0 = kt << 7;
    const int ktn = (kt < hi) ? kt + 1 : hi;  // clamped (uniform vmcnt counts)
    WAITV(4);  // V(kt) regs ready; K(kt) still in flight
    __builtin_amdgcn_sched_barrier(0);
    __builtin_amdgcn_s_barrier();  // A: all waves done compute(kt-1)
    {
      const int kv = pr_ * 2, d0 = dc * 8;
      unsigned av[4] = {va.x, va.y, va.z, va.w};
      unsigned bv[4] = {vb.x, vb.y, vb.z, vb.w};
      unsigned cv[4] = {vc.x, vc.y, vc.z, vc.w};
      unsigned dv[4] = {vd.x, vd.y, vd.z, vd.w};
#pragma unroll
      for (int j = 0; j < 4; ++j) {
        *(unsigned*)&Vt[d0 + j * 2][kv] = (av[j] & 0xffffu) | (bv[j] << 16);
        *(unsigned*)&Vt[d0 + j * 2 + 1][kv] = (av[j] >> 16) | (bv[j] & 0xffff0000u);
        *(unsigned*)&Vt[d0 + j * 2][kv + 64] = (cv[j] & 0xffffu) | (dv[j] << 16);
        *(unsigned*)&Vt[d0 + j * 2 + 1][kv + 64] = (cv[j] >> 16) | (dv[j] & 0xffff0000u);
      }
    }
    WAITV(0);  // K(kt) landed in Ks[buf]
    asm volatile("s_waitcnt lgkmcnt(0)" ::: "memory");  // own Vt writes done
    __builtin_amdgcn_sched_barrier(0);
    __builtin_amdgcn_s_barrier();  // B: staging published
    loadV(ktn << 7, va2, vb2, vc2, vd2);
    __builtin_amdgcn_sched_barrier(0);
    issueK(ktn << 7, buf ^ 1);
    __builtin_amdgcn_sched_barrier(0);
    if (kt >= lo_w && kt <= hi_w) {
      u32* pbase = &Ps[w][0];
#pragma unroll
      for (int c4 = 0; c4 < 8; ++c4) {
        f32x4 sa = {};
#pragma unroll
        for (int ks = 0; ks < 4; ++ks) {
          const int krow = c4 * 16 + l16;
          const int ch = (ks * 4 + lg) ^ (krow & 7);
          bf16x8 kf = *(const bf16x8*)(Ks[buf] + krow * 256 + ch * 16);
          sa = __builtin_amdgcn_mfma_f32_16x16x32_bf16(kf, qf[ks], sa, 0, 0, 0);
        }
        const int kj_base = kv0 + c4 * 16 + lg * 4;
        float p[4];
#pragma unroll
        for (int r = 0; r < 4; ++r) {
          unsigned diff = (unsigned)(qi - (kj_base + r));
          float v = sa[r] * SC2;
          v = (diff < WIN) ? v : -1e30f;
          p[r] = __builtin_amdgcn_exp2f(v);
        }
        const u32 w0 = (u32)f2bf(p[0]) | ((u32)f2bf(p[1]) << 16);
        const u32 w1 = (u32)f2bf(p[2]) | ((u32)f2bf(p[3]) << 16);
        const int pw = l16 * 68 + c4 * 8 + lg * 2;
        pbase[pw] = w0;
        pbase[pw + 1] = w1;
      }
      asm volatile("s_waitcnt lgkmcnt(0)" ::: "memory");
      __builtin_amdgcn_sched_barrier(0);
#pragma unroll
      for (int ks = 0; ks < 4; ++ks) {
        uint4 pr2 = *(const uint4*)&Ps[w][l16 * 68 + ks * 16 + lg * 4];
        bf16x8 pf = __builtin_bit_cast(bf16x8, pr2);
#pragma unroll
        for (int dt = 0; dt < 8; ++dt) {
          bf16x8 vf = *(const bf16x8*)(&Vt[dt * 16 + l16][ks * 32 + lg * 8]);
          oacc[dt] = __builtin_amdgcn_mfma_f32_16x16x32_bf16(pf, vf, oacc[dt], 0, 0, 0);
        }
        ldacc = __builtin_amdgcn_mfma_f32_16x16x32_bf16(pf, ones, ldacc, 0, 0, 0);
      }
    }
    va = va2; vb = vb2; vc = vc2; vd = vd2;
  }
  const int qr = q0w + lg * 4;
  u16* orow = attnO + ((size_t)(b * S_LEN + qr) * DIM) + h * HD;
#pragma unroll
  for (int r = 0; r < 4; ++r) {
    float inv = 1.f / ldacc[r];
#pragma unroll
    for (int dt = 0; dt < 8; ++dt)
      orow[(size_t)r * DIM + dt * 16 + l16] = f2bf(oacc[dt][r] * inv);
  }
}

extern "C" void kernel_launch(void* const* d_in, const int* in_sizes, int n_in,
                              void* d_out, int out_size, void* d_ws, size_t ws_size,
                              hipStream_t stream) {
  const float* x = (const float*)d_in[0];
  const float* w_qkv = (const float*)d_in[1];
  const float* w_out = (const float*)d_in[2];
  float* out = (float*)d_out;

  char* ws = (char*)d_ws;
  size_t off = 0;
  auto alloc = [&](size_t bytes) {
    void* p = ws + off;
    off = (off + bytes + 255) & ~(size_t)255;
    return p;
  };
  const size_t rows = 2ull * S_LEN;                // 4096
  u16* wqkvb = (u16*)alloc(3ull * DIM * DIM * 2);  // 25.2 MB (reused as attn out)
  u16* woutb = (u16*)alloc((size_t)DIM * DIM * 2); // 8.4 MB
  u16* xb    = (u16*)alloc(rows * DIM * 2);        // 16.8 MB
  u16* qkvb  = (u16*)alloc(rows * 3 * DIM * 2);    // 50.3 MB
  float* cosT = (float*)alloc((size_t)S_LEN * 64 * 4);
  float* sinT = (float*)alloc((size_t)S_LEN * 64 * 4);

  const int na = 3 * DIM * DIM, nb = DIM * DIM, nc = (int)(rows * DIM);
  const int nCvt = (na + nb + nc) / 1024;
  cvt3tab_kernel<<<nCvt + (S_LEN * 64) / 256, 256, 0, stream>>>(
      w_qkv, wqkvb, na, w_out, woutb, nb, x, xb, nc, cosT, sinT, nCvt);
  // QKV projection: 128x384, grid 512; XCD n-pinned B panels
  gemm8<384, u16><<<(int)(rows / 128) * (QKVD / 384), 512, 0, stream>>>(
      xb, wqkvb, qkvb, (int)rows, QKVD, DIM);
  // RoPE in-place on K only (Q rope'd inside attn)
  ropek_kernel<<<(int)(rows / 2), 256, 0, stream>>>(qkvb, cosT, sinT);
  // attention: QBLK=128, KVBLK=128, 512 blocks, chunked XCD mapping
  u16* attnb = wqkvb;
  attn_kernel<<<2 * NH * (S_LEN / 128), 512, 0, stream>>>(qkvb, attnb, cosT, sinT);
  // output projection: 128x256, grid 256 = 1 round; m-chunked
  gemm8<256, float><<<(int)(rows / 128) * (DIM / 256), 512, 0, stream>>>(
      attnb, woutb, out, (int)rows, DIM, DIM);
}

// Round 20
// 228.019 us; speedup vs baseline: 1.0523x; 1.0523x over previous
//
#include <hip/hip_runtime.h>

#define S_LEN 2048
#define DIM 2048
#define NH 16
#define HD 128
#define WIN 512
#define QKVD (3 * DIM)  // 6144

typedef unsigned short u16;
typedef unsigned int u32;
typedef __bf16 bf16x8 __attribute__((ext_vector_type(8)));
typedef float f32x4 __attribute__((ext_vector_type(4)));

__device__ __forceinline__ u16 f2bf(float f) {
  unsigned u = __builtin_bit_cast(unsigned, f);
  u += 0x7FFFu + ((u >> 16) & 1u);
  return (u16)(u >> 16);
}
__device__ __forceinline__ float bf2f(u16 b) {
  return __builtin_bit_cast(float, (unsigned)b << 16);
}
__device__ __forceinline__ void async16(const void* g, void* l) {
  __builtin_amdgcn_global_load_lds((__attribute__((address_space(1))) void*)g,
                                   (__attribute__((address_space(3))) void*)l,
                                   16, 0, 0);
}
#define WAITV(N) asm volatile("s_waitcnt vmcnt(" #N ")" ::: "memory")

// ---- merged fp32->bf16 convert (3 arrays) + RoPE table, one launch --------
__global__ __launch_bounds__(256) void cvt3tab_kernel(
    const float* __restrict__ a, u16* __restrict__ oa, int na,
    const float* __restrict__ b, u16* __restrict__ ob, int nb,
    const float* __restrict__ c, u16* __restrict__ oc, int nc,
    float* __restrict__ cosT, float* __restrict__ sinT, int nCvt) {
  if ((int)blockIdx.x >= nCvt) {
    int idx = ((int)blockIdx.x - nCvt) * 256 + threadIdx.x;  // S*64 entries
    int s = idx >> 6, j = idx & 63;
    double freq = exp((double)j * -0.14391156831212787);  // -ln(10000)/64
    double ang = (double)s * freq;
    cosT[idx] = (float)cos(ang);
    sinT[idx] = (float)sin(ang);
    return;
  }
  int i = (blockIdx.x * 256 + threadIdx.x) * 4;
  const float* src;
  u16* dst;
  if (i < na) { src = a + i; dst = oa + i; }
  else if (i < na + nb) { src = b + (i - na); dst = ob + (i - na); }
  else if (i < na + nb + nc) { src = c + (i - na - nb); dst = oc + (i - na - nb); }
  else return;
  float4 v = *(const float4*)src;
  ushort4 o;
  o.x = f2bf(v.x); o.y = f2bf(v.y); o.z = f2bf(v.z); o.w = f2bf(v.w);
  *(ushort4*)dst = o;
}

// ============ 128xBN 4-phase/K-tile GEMM: C = A * B^T ============
// BM=128, BN in {384, 256}; 512 thr (8 waves, 2M x 4N), BK=64, dbuf LDS.
// r8-proven stagger: ph1->B0(t+1), ph2->B1(t+1), ph3->A1(t+1), ph4->A0(t+2).
// FIFO waits per BN: 384 [3,3,1,1] -> 5/7/-/5 ; 256 [2,2,1,1] -> 4/5/-/4.
template <int BN, typename TO>
__global__ __launch_bounds__(512, 2) void gemm8(const u16* __restrict__ A,
                                                const u16* __restrict__ B,
                                                TO* __restrict__ C,
                                                int M, int N, int K) {
  constexpr int ABY = 128 * 128;
  constexpr int BBY = BN * 128;
  constexpr int BLO = BN / 128;
  __shared__ __align__(16) char Al[2 * ABY];
  __shared__ __align__(16) char Bl[2 * BBY];

  const int tiles_n = N / BN;
  const int tiles_m = M >> 7;
  int m0, n0;
  if constexpr (BN == 384) {       // n-pinned (QKV, r15-proven)
    const int npx = tiles_n >> 3;
    const int xcd = (int)blockIdx.x & 7;
    const int idx = (int)blockIdx.x >> 3;
    m0 = (idx % tiles_m) << 7;
    n0 = (xcd * npx + idx / tiles_m) * BN;
  } else {                         // m-chunked (out-proj, r13-proven)
    const int nwg = gridDim.x;
    const int wg = ((int)blockIdx.x & 7) * (nwg >> 3) + ((int)blockIdx.x >> 3);
    m0 = (wg / tiles_n) << 7;
    n0 = (wg % tiles_n) * BN;
  }
  const int t = threadIdx.x;
  const int l = t & 63, w = t >> 6;
  const int wr = w >> 2, wc = w & 3;
  const int l16 = l & 15, lg = l >> 4;
  const u16* Asrc = A + (size_t)m0 * K;
  const u16* Bsrc = B + (size_t)n0 * K;

  auto stA = [&](int kcol, int half, int b) {
    int rih = t >> 3, ch = t & 7;
    int row = half * 64 + rih;
    async16(Asrc + (size_t)row * K + kcol + ((ch ^ (row & 7)) << 3),
            Al + b * ABY + row * 128 + ch * 16);
  };
  auto stB = [&](int kcol, int half, int b) {
#pragma unroll
    for (int j = 0; j < BLO; ++j) {
      int c = t + j * 512;
      int rih = c >> 3, ch = c & 7;
      int row = half * (BN / 2) + rih;
      async16(Bsrc + (size_t)row * K + kcol + ((ch ^ (row & 7)) << 3),
              Bl + b * BBY + row * 128 + ch * 16);
    }
  };

  f32x4 acc[4][2 * BLO] = {};
  bf16x8 af[2][2];
  bf16x8 bfr[2][BLO][2];

  auto rdA = [&](int b, int mh) {
#pragma unroll
    for (int m = 0; m < 2; ++m)
#pragma unroll
      for (int ks = 0; ks < 2; ++ks) {
        int row = wr * 64 + mh * 32 + m * 16 + l16;
        int ch = ks * 4 + lg;
        af[m][ks] = *(const bf16x8*)(Al + b * ABY + row * 128 + ((ch ^ (row & 7)) << 4));
      }
  };
  auto rdB = [&](int b, int nh) {
#pragma unroll
    for (int n = 0; n < BLO; ++n)
#pragma unroll
      for (int ks = 0; ks < 2; ++ks) {
        int row = wc * (BN / 4) + nh * (BN / 8) + n * 16 + l16;
        int ch = ks * 4 + lg;
        bfr[nh][n][ks] = *(const bf16x8*)(Bl + b * BBY + row * 128 + ((ch ^ (row & 7)) << 4));
      }
  };
  auto mm = [&](int mh, int nh) {
#pragma unroll
    for (int m = 0; m < 2; ++m)
#pragma unroll
      for (int n = 0; n < BLO; ++n)
#pragma unroll
        for (int ks = 0; ks < 2; ++ks)
          acc[mh * 2 + m][nh * BLO + n] = __builtin_amdgcn_mfma_f32_16x16x32_bf16(
              af[m][ks], bfr[nh][n][ks], acc[mh * 2 + m][nh * BLO + n], 0, 0, 0);
  };

  const int NT = K >> 6;
  stA(0, 0, 0); stB(0, 0, 0); stB(0, 1, 0); stA(0, 1, 0); stA(64, 0, 1);
  if constexpr (BN == 384) WAITV(5); else WAITV(4);
  __builtin_amdgcn_s_barrier();

  for (int kt = 0; kt < NT; ++kt) {
    const int b = kt & 1, nb = b ^ 1;
    const int k1 = ((kt + 1 < NT) ? kt + 1 : kt) << 6;
    const int k2 = ((kt + 2 < NT) ? kt + 2 : kt) << 6;
    rdA(b, 0); rdB(b, 0);
    stB(k1, 0, nb);
    __builtin_amdgcn_s_barrier();
    __builtin_amdgcn_s_setprio(1); mm(0, 0); __builtin_amdgcn_s_setprio(0);
    if constexpr (BN == 384) WAITV(5); else WAITV(4);  // drain B1(t)
    __builtin_amdgcn_s_barrier();
    rdB(b, 1);
    stB(k1, 1, nb);
    __builtin_amdgcn_s_barrier();
    __builtin_amdgcn_s_setprio(1); mm(0, 1); __builtin_amdgcn_s_setprio(0);
    if constexpr (BN == 384) WAITV(7); else WAITV(5);  // drain A1(t)
    __builtin_amdgcn_s_barrier();
    rdA(b, 1);
    stA(k1, 1, nb);
    __builtin_amdgcn_s_barrier();
    __builtin_amdgcn_s_setprio(1); mm(1, 0); __builtin_amdgcn_s_setprio(0);
    __builtin_amdgcn_s_barrier();
    stA(k2, 0, b);
    __builtin_amdgcn_s_barrier();
    __builtin_amdgcn_s_setprio(1); mm(1, 1); __builtin_amdgcn_s_setprio(0);
    if constexpr (BN == 384) WAITV(5); else WAITV(4);  // drain A0/B0(t+1)
    __builtin_amdgcn_s_barrier();
  }

  const int rb = m0 + wr * 64 + lg * 4;
  const int cb = n0 + wc * (BN / 4) + l16;
#pragma unroll
  for (int mi = 0; mi < 4; ++mi)
#pragma unroll
    for (int ni = 0; ni < 2 * BLO; ++ni)
#pragma unroll
      for (int r = 0; r < 4; ++r) {
        float v = acc[mi][ni][r];
        size_t idx2 = (size_t)(rb + mi * 16 + r) * N + cb + ni * 16;
        if constexpr (sizeof(TO) == 2) C[idx2] = f2bf(v);
        else C[idx2] = v;
      }
}

// -------- RoPE in-place on K ONLY (Q is rope'd in-register inside attn) -----
__global__ __launch_bounds__(256) void ropek_kernel(u16* __restrict__ qkv,
                                                    const float* __restrict__ cosT,
                                                    const float* __restrict__ sinT) {
  const int row = blockIdx.x * 2 + (threadIdx.x >> 7);  // b*S + s
  const int s = row & (S_LEN - 1);
  const int slot = threadIdx.x & 127;
  const int h = slot >> 3;
  const int c = slot & 7;
  u16* p = qkv + (size_t)row * QKVD + DIM + h * HD + c * 8;  // K part
  const float* cp = cosT + (s << 6) + c * 8;
  const float* sp = sinT + (s << 6) + c * 8;
  const float4 c0 = *(const float4*)cp, c1 = *(const float4*)(cp + 4);
  const float4 s0 = *(const float4*)sp, s1 = *(const float4*)(sp + 4);
  float cs[8] = {c0.x, c0.y, c0.z, c0.w, c1.x, c1.y, c1.z, c1.w};
  float sn[8] = {s0.x, s0.y, s0.z, s0.w, s1.x, s1.y, s1.z, s1.w};
  uint4 lo = *(const uint4*)p;
  uint4 hi = *(const uint4*)(p + 64);
  unsigned lw[4] = {lo.x, lo.y, lo.z, lo.w};
  unsigned hw[4] = {hi.x, hi.y, hi.z, hi.w};
  unsigned ol[4], oh[4];
#pragma unroll
  for (int j = 0; j < 4; ++j) {
    float x1a = bf2f((u16)(lw[j] & 0xffffu)), x1b = bf2f((u16)(lw[j] >> 16));
    float x2a = bf2f((u16)(hw[j] & 0xffffu)), x2b = bf2f((u16)(hw[j] >> 16));
    float ca = cs[j * 2], cb = cs[j * 2 + 1];
    float sa = sn[j * 2], sb = sn[j * 2 + 1];
    ol[j] = (u32)f2bf(x1a * ca - x2a * sa) | ((u32)f2bf(x1b * cb - x2b * sb) << 16);
    oh[j] = (u32)f2bf(x2a * ca + x1a * sa) | ((u32)f2bf(x2b * cb + x1b * sb) << 16);
  }
  *(uint4*)p = (uint4){ol[0], ol[1], ol[2], ol[3]};
  *(uint4*)(p + 64) = (uint4){oh[0], oh[1], oh[2], oh[3]};
}

// -------- sliding-window flash attention: QBLK=256, fragment reuse x2 ------
// grid = (B*H) * (S/256) = 256 blocks (1/CU). 8 waves x 32 q-rows (2 groups
// of 16). kf/vf LDS reads amortized over both groups.
__global__ __launch_bounds__(512, 1) void attn_kernel(const u16* __restrict__ qkv,
                                                      u16* __restrict__ attnO,
                                                      const float* __restrict__ cosT,
                                                      const float* __restrict__ sinT) {
  const int nwg = gridDim.x;  // 256
  const int wg = ((int)blockIdx.x & 7) * (nwg >> 3) + ((int)blockIdx.x >> 3);
  const int qt = wg & 7;     // 8 q-tiles of 256
  const int bh = wg >> 3;
  const int q0 = qt << 8;
  const int b = bh >> 4, h = bh & 15;
  const u16* Qp = qkv + (size_t)b * S_LEN * QKVD + h * HD;
  const u16* Kp = Qp + DIM;
  const u16* Vp = Qp + 2 * DIM;
  __shared__ __align__(16) char Ks[2][64 * 256];    // dbuf XOR-swizzled K
  __shared__ __align__(16) u16 Vt[128][72];         // transposed V, padded
  __shared__ __align__(16) u32 Ps[8][2][16 * 36];   // per-wave, per-group P
  const int t = threadIdx.x;
  const int w = t >> 6, l = t & 63;
  const int l16 = l & 15, lg = l >> 4;
  const int q0w = q0 + w * 32;  // wave owns 32 rows (2 groups of 16)
  const bf16x8 ones = __builtin_bit_cast(bf16x8,
      (uint4){0x3F803F80u, 0x3F803F80u, 0x3F803F80u, 0x3F803F80u});
  bf16x8 qf[2][4];
#pragma unroll
  for (int g = 0; g < 2; ++g) {
    const int srow = q0w + g * 16 + l16;
    const u16* qrow = Qp + (size_t)srow * QKVD;
#pragma unroll
    for (int ks = 0; ks < 4; ++ks) qf[g][ks] = *(const bf16x8*)(qrow + ks * 32 + lg * 8);
    // in-register RoPE on Q
    const float* cbase = cosT + (srow << 6) + lg * 8;
    const float* sbase = sinT + (srow << 6) + lg * 8;
#pragma unroll
    for (int ks = 0; ks < 2; ++ks) {
      const float4 ca = *(const float4*)(cbase + ks * 32);
      const float4 cb2 = *(const float4*)(cbase + ks * 32 + 4);
      const float4 sa = *(const float4*)(sbase + ks * 32);
      const float4 sb2 = *(const float4*)(sbase + ks * 32 + 4);
      const float cs[8] = {ca.x, ca.y, ca.z, ca.w, cb2.x, cb2.y, cb2.z, cb2.w};
      const float sn[8] = {sa.x, sa.y, sa.z, sa.w, sb2.x, sb2.y, sb2.z, sb2.w};
      const uint4 lv = __builtin_bit_cast(uint4, qf[g][ks]);
      const uint4 hv = __builtin_bit_cast(uint4, qf[g][ks + 2]);
      const unsigned li[4] = {lv.x, lv.y, lv.z, lv.w};
      const unsigned hi2[4] = {hv.x, hv.y, hv.z, hv.w};
      unsigned lw[4], hw[4];
#pragma unroll
      for (int p2 = 0; p2 < 4; ++p2) {
        float f1a = bf2f((u16)(li[p2] & 0xffffu)), f1b = bf2f((u16)(li[p2] >> 16));
        float f2a = bf2f((u16)(hi2[p2] & 0xffffu)), f2b = bf2f((u16)(hi2[p2] >> 16));
        lw[p2] = (u32)f2bf(f1a * cs[p2 * 2] - f2a * sn[p2 * 2]) |
                 ((u32)f2bf(f1b * cs[p2 * 2 + 1] - f2b * sn[p2 * 2 + 1]) << 16);
        hw[p2] = (u32)f2bf(f2a * cs[p2 * 2] + f1a * sn[p2 * 2]) |
                 ((u32)f2bf(f2b * cs[p2 * 2 + 1] + f1b * sn[p2 * 2 + 1]) << 16);
      }
      qf[g][ks] = __builtin_bit_cast(bf16x8, (uint4){lw[0], lw[1], lw[2], lw[3]});
      qf[g][ks + 2] = __builtin_bit_cast(bf16x8, (uint4){hw[0], hw[1], hw[2], hw[3]});
    }
  }
  f32x4 oacc[2][8] = {};
  f32x4 ldacc[2] = {};
  const int lo = max(0, (q0 - (WIN - 1)) >> 6);
  const int hi = (q0 + 255) >> 6;
  const int lo_w = max(0, (q0w - (WIN - 1)) >> 6);
  const int hi_w = (q0w + 31) >> 6;
  const float SC2 = 0.12751744654f;  // log2(e)/sqrt(128)
  const int dc = t & 15, pr_ = t >> 4;  // V-stage: d-chunk, kv-pair

  auto loadV = [&](int kv0, uint4& va, uint4& vb) {
    va = *(const uint4*)(Vp + (size_t)(kv0 + pr_ * 2) * QKVD + dc * 8);
    vb = *(const uint4*)(Vp + (size_t)(kv0 + pr_ * 2 + 1) * QKVD + dc * 8);
  };
  auto issueK = [&](int kv0, int buf) {
#pragma unroll
    for (int i = 0; i < 2; ++i) {
      int c = t + (i << 9);
      int row = c >> 4, ch = c & 15;
      int sch = ch ^ (row & 7);
      async16(Kp + (size_t)(kv0 + row) * QKVD + sch * 8, Ks[buf] + c * 16);
    }
  };

  uint4 va, vb, va2, vb2;
  loadV(lo << 6, va, vb);
  __builtin_amdgcn_sched_barrier(0);
  issueK(lo << 6, 0);
  __builtin_amdgcn_sched_barrier(0);

  for (int kt = lo; kt <= hi; ++kt) {
    const int buf = (kt - lo) & 1;
    const int kv0 = kt << 6;
    const int ktn = (kt < hi) ? kt + 1 : hi;
    WAITV(2);  // V(kt) regs ready; K(kt) still in flight
    __builtin_amdgcn_sched_barrier(0);
    __builtin_amdgcn_s_barrier();  // A: all waves done compute(kt-1)
    {
      const int kv = pr_ * 2, d0 = dc * 8;
      unsigned av[4] = {va.x, va.y, va.z, va.w};
      unsigned bv[4] = {vb.x, vb.y, vb.z, vb.w};
#pragma unroll
      for (int j = 0; j < 4; ++j) {
        *(unsigned*)&Vt[d0 + j * 2][kv] = (av[j] & 0xffffu) | (bv[j] << 16);
        *(unsigned*)&Vt[d0 + j * 2 + 1][kv] = (av[j] >> 16) | (bv[j] & 0xffff0000u);
      }
    }
    WAITV(0);  // K(kt) landed in Ks[buf]
    asm volatile("s_waitcnt lgkmcnt(0)" ::: "memory");
    __builtin_amdgcn_sched_barrier(0);
    __builtin_amdgcn_s_barrier();  // B: staging published
    loadV(ktn << 6, va2, vb2);
    __builtin_amdgcn_sched_barrier(0);
    issueK(ktn << 6, buf ^ 1);
    __builtin_amdgcn_sched_barrier(0);
    if (kt >= lo_w && kt <= hi_w) {
      // QK^T: kf read ONCE per (c4,ks), feeds both q-groups
#pragma unroll
      for (int c4 = 0; c4 < 4; ++c4) {
        f32x4 sa0 = {}, sa1 = {};
#pragma unroll
        for (int ks = 0; ks < 4; ++ks) {
          const int krow = c4 * 16 + l16;
          const int ch = (ks * 4 + lg) ^ (krow & 7);
          bf16x8 kf = *(const bf16x8*)(Ks[buf] + krow * 256 + ch * 16);
          sa0 = __builtin_amdgcn_mfma_f32_16x16x32_bf16(kf, qf[0][ks], sa0, 0, 0, 0);
          sa1 = __builtin_amdgcn_mfma_f32_16x16x32_bf16(kf, qf[1][ks], sa1, 0, 0, 0);
        }
        const int kj_base = kv0 + c4 * 16 + lg * 4;
#pragma unroll
        for (int g = 0; g < 2; ++g) {
          const f32x4 sa = g ? sa1 : sa0;
          const int qi = q0w + g * 16 + l16;
          float p[4];
#pragma unroll
          for (int r = 0; r < 4; ++r) {
            unsigned diff = (unsigned)(qi - (kj_base + r));
            float v = sa[r] * SC2;
            v = (diff < WIN) ? v : -1e30f;
            p[r] = __builtin_amdgcn_exp2f(v);
          }
          const u32 w0 = (u32)f2bf(p[0]) | ((u32)f2bf(p[1]) << 16);
          const u32 w1 = (u32)f2bf(p[2]) | ((u32)f2bf(p[3]) << 16);
          const int pw = l16 * 36 + c4 * 8 + lg * 2;
          Ps[w][g][pw] = w0;
          Ps[w][g][pw + 1] = w1;
        }
      }
      asm volatile("s_waitcnt lgkmcnt(0)" ::: "memory");
      __builtin_amdgcn_sched_barrier(0);
      // PV: vf read ONCE per (ks,dt), feeds both q-groups
#pragma unroll
      for (int ks = 0; ks < 2; ++ks) {
        uint4 p0 = *(const uint4*)&Ps[w][0][l16 * 36 + ks * 16 + lg * 4];
        uint4 p1 = *(const uint4*)&Ps[w][1][l16 * 36 + ks * 16 + lg * 4];
        bf16x8 pf0 = __builtin_bit_cast(bf16x8, p0);
        bf16x8 pf1 = __builtin_bit_cast(bf16x8, p1);
#pragma unroll
        for (int dt = 0; dt < 8; ++dt) {
          bf16x8 vf = *(const bf16x8*)(&Vt[dt * 16 + l16][ks * 32 + lg * 8]);
          oacc[0][dt] = __builtin_amdgcn_mfma_f32_16x16x32_bf16(pf0, vf, oacc[0][dt], 0, 0, 0);
          oacc[1][dt] = __builtin_amdgcn_mfma_f32_16x16x32_bf16(pf1, vf, oacc[1][dt], 0, 0, 0);
        }
        ldacc[0] = __builtin_amdgcn_mfma_f32_16x16x32_bf16(pf0, ones, ldacc[0], 0, 0, 0);
        ldacc[1] = __builtin_amdgcn_mfma_f32_16x16x32_bf16(pf1, ones, ldacc[1], 0, 0, 0);
      }
    }
    va = va2; vb = vb2;
  }
#pragma unroll
  for (int g = 0; g < 2; ++g) {
    const int qr = q0w + g * 16 + lg * 4;
    u16* orow = attnO + ((size_t)(b * S_LEN + qr) * DIM) + h * HD;
#pragma unroll
    for (int r = 0; r < 4; ++r) {
      float inv = 1.f / ldacc[g][r];
#pragma unroll
      for (int dt = 0; dt < 8; ++dt)
        orow[(size_t)r * DIM + dt * 16 + l16] = f2bf(oacc[g][dt][r] * inv);
    }
  }
}

extern "C" void kernel_launch(void* const* d_in, const int* in_sizes, int n_in,
                              void* d_out, int out_size, void* d_ws, size_t ws_size,
                              hipStream_t stream) {
  const float* x = (const float*)d_in[0];
  const float* w_qkv = (const float*)d_in[1];
  const float* w_out = (const float*)d_in[2];
  float* out = (float*)d_out;

  char* ws = (char*)d_ws;
  size_t off = 0;
  auto alloc = [&](size_t bytes) {
    void* p = ws + off;
    off = (off + bytes + 255) & ~(size_t)255;
    return p;
  };
  const size_t rows = 2ull * S_LEN;                // 4096
  u16* wqkvb = (u16*)alloc(3ull * DIM * DIM * 2);  // 25.2 MB (reused as attn out)
  u16* woutb = (u16*)alloc((size_t)DIM * DIM * 2); // 8.4 MB
  u16* xb    = (u16*)alloc(rows * DIM * 2);        // 16.8 MB
  u16* qkvb  = (u16*)alloc(rows * 3 * DIM * 2);    // 50.3 MB
  float* cosT = (float*)alloc((size_t)S_LEN * 64 * 4);
  float* sinT = (float*)alloc((size_t)S_LEN * 64 * 4);

  const int na = 3 * DIM * DIM, nb = DIM * DIM, nc = (int)(rows * DIM);
  const int nCvt = (na + nb + nc) / 1024;
  cvt3tab_kernel<<<nCvt + (S_LEN * 64) / 256, 256, 0, stream>>>(
      w_qkv, wqkvb, na, w_out, woutb, nb, x, xb, nc, cosT, sinT, nCvt);
  // QKV projection: 128x384, grid 512; XCD n-pinned B panels
  gemm8<384, u16><<<(int)(rows / 128) * (QKVD / 384), 512, 0, stream>>>(
      xb, wqkvb, qkvb, (int)rows, QKVD, DIM);
  // RoPE in-place on K only (Q rope'd inside attn)
  ropek_kernel<<<(int)(rows / 2), 256, 0, stream>>>(qkvb, cosT, sinT);
  // attention: QBLK=256, 256 blocks (1/CU), fragment reuse x2
  u16* attnb = wqkvb;
  attn_kernel<<<2 * NH * (S_LEN / 256), 512, 0, stream>>>(qkvb, attnb, cosT, sinT);
  // output projection: 128x256, grid 256 = 1 round; m-chunked
  gemm8<256, float><<<(int)(rows / 128) * (DIM / 256), 512, 0, stream>>>(
      attnb, woutb, out, (int)rows, DIM, DIM);
}

// Round 21
// 224.508 us; speedup vs baseline: 1.0687x; 1.0156x over previous
//
#include <hip/hip_runtime.h>

#define S_LEN 2048
#define DIM 2048
#define NH 16
#define HD 128
#define WIN 512
#define QKVD (3 * DIM)  // 6144

typedef unsigned short u16;
typedef unsigned int u32;
typedef __bf16 bf16x8 __attribute__((ext_vector_type(8)));
typedef float f32x4 __attribute__((ext_vector_type(4)));

__device__ __forceinline__ u16 f2bf(float f) {
  unsigned u = __builtin_bit_cast(unsigned, f);
  u += 0x7FFFu + ((u >> 16) & 1u);
  return (u16)(u >> 16);
}
__device__ __forceinline__ float bf2f(u16 b) {
  return __builtin_bit_cast(float, (unsigned)b << 16);
}
__device__ __forceinline__ void async16(const void* g, void* l) {
  __builtin_amdgcn_global_load_lds((__attribute__((address_space(1))) void*)g,
                                   (__attribute__((address_space(3))) void*)l,
                                   16, 0, 0);
}
#define WAITV(N) asm volatile("s_waitcnt vmcnt(" #N ")" ::: "memory")

// ---- merged fp32->bf16 convert (3 arrays) + RoPE table, one launch --------
__global__ __launch_bounds__(256) void cvt3tab_kernel(
    const float* __restrict__ a, u16* __restrict__ oa, int na,
    const float* __restrict__ b, u16* __restrict__ ob, int nb,
    const float* __restrict__ c, u16* __restrict__ oc, int nc,
    float* __restrict__ cosT, float* __restrict__ sinT, int nCvt) {
  if ((int)blockIdx.x >= nCvt) {
    int idx = ((int)blockIdx.x - nCvt) * 256 + threadIdx.x;  // S*64 entries
    int s = idx >> 6, j = idx & 63;
    double freq = exp((double)j * -0.14391156831212787);  // -ln(10000)/64
    double ang = (double)s * freq;
    cosT[idx] = (float)cos(ang);
    sinT[idx] = (float)sin(ang);
    return;
  }
  int i = (blockIdx.x * 256 + threadIdx.x) * 4;
  const float* src;
  u16* dst;
  if (i < na) { src = a + i; dst = oa + i; }
  else if (i < na + nb) { src = b + (i - na); dst = ob + (i - na); }
  else if (i < na + nb + nc) { src = c + (i - na - nb); dst = oc + (i - na - nb); }
  else return;
  float4 v = *(const float4*)src;
  ushort4 o;
  o.x = f2bf(v.x); o.y = f2bf(v.y); o.z = f2bf(v.z); o.w = f2bf(v.w);
  *(ushort4*)dst = o;
}

// ============ 128xBN 4-phase/K-tile GEMM: C = A * B^T ============
// BM=128, BN in {384, 256}; 512 thr (8 waves, 2M x 4N), BK=64, dbuf LDS.
// r8-proven stagger: ph1->B0(t+1), ph2->B1(t+1), ph3->A1(t+1), ph4->A0(t+2).
// FIFO waits per BN: 384 [3,3,1,1] -> 5/7/-/5 ; 256 [2,2,1,1] -> 4/5/-/4.
// BARRIER DIET (r20): the pre-MFMA barrier is provably redundant — per-wave
// vmcnt FIFO + the post-wait barrier give all cross-wave publish guarantees;
// every staged region's last reader is >=2 barriers upstream. 4 barriers/tile.
template <int BN, typename TO>
__global__ __launch_bounds__(512, 2) void gemm8(const u16* __restrict__ A,
                                                const u16* __restrict__ B,
                                                TO* __restrict__ C,
                                                int M, int N, int K) {
  constexpr int ABY = 128 * 128;
  constexpr int BBY = BN * 128;
  constexpr int BLO = BN / 128;
  __shared__ __align__(16) char Al[2 * ABY];
  __shared__ __align__(16) char Bl[2 * BBY];

  const int tiles_n = N / BN;
  const int tiles_m = M >> 7;
  int m0, n0;
  if constexpr (BN == 384) {       // n-pinned (QKV, r15-proven)
    const int npx = tiles_n >> 3;
    const int xcd = (int)blockIdx.x & 7;
    const int idx = (int)blockIdx.x >> 3;
    m0 = (idx % tiles_m) << 7;
    n0 = (xcd * npx + idx / tiles_m) * BN;
  } else {                         // m-chunked (out-proj, r13-proven)
    const int nwg = gridDim.x;
    const int wg = ((int)blockIdx.x & 7) * (nwg >> 3) + ((int)blockIdx.x >> 3);
    m0 = (wg / tiles_n) << 7;
    n0 = (wg % tiles_n) * BN;
  }
  const int t = threadIdx.x;
  const int l = t & 63, w = t >> 6;
  const int wr = w >> 2, wc = w & 3;
  const int l16 = l & 15, lg = l >> 4;
  const u16* Asrc = A + (size_t)m0 * K;
  const u16* Bsrc = B + (size_t)n0 * K;

  auto stA = [&](int kcol, int half, int b) {
    int rih = t >> 3, ch = t & 7;
    int row = half * 64 + rih;
    async16(Asrc + (size_t)row * K + kcol + ((ch ^ (row & 7)) << 3),
            Al + b * ABY + row * 128 + ch * 16);
  };
  auto stB = [&](int kcol, int half, int b) {
#pragma unroll
    for (int j = 0; j < BLO; ++j) {
      int c = t + j * 512;
      int rih = c >> 3, ch = c & 7;
      int row = half * (BN / 2) + rih;
      async16(Bsrc + (size_t)row * K + kcol + ((ch ^ (row & 7)) << 3),
              Bl + b * BBY + row * 128 + ch * 16);
    }
  };

  f32x4 acc[4][2 * BLO] = {};
  bf16x8 af[2][2];
  bf16x8 bfr[2][BLO][2];

  auto rdA = [&](int b, int mh) {
#pragma unroll
    for (int m = 0; m < 2; ++m)
#pragma unroll
      for (int ks = 0; ks < 2; ++ks) {
        int row = wr * 64 + mh * 32 + m * 16 + l16;
        int ch = ks * 4 + lg;
        af[m][ks] = *(const bf16x8*)(Al + b * ABY + row * 128 + ((ch ^ (row & 7)) << 4));
      }
  };
  auto rdB = [&](int b, int nh) {
#pragma unroll
    for (int n = 0; n < BLO; ++n)
#pragma unroll
      for (int ks = 0; ks < 2; ++ks) {
        int row = wc * (BN / 4) + nh * (BN / 8) + n * 16 + l16;
        int ch = ks * 4 + lg;
        bfr[nh][n][ks] = *(const bf16x8*)(Bl + b * BBY + row * 128 + ((ch ^ (row & 7)) << 4));
      }
  };
  auto mm = [&](int mh, int nh) {
#pragma unroll
    for (int m = 0; m < 2; ++m)
#pragma unroll
      for (int n = 0; n < BLO; ++n)
#pragma unroll
        for (int ks = 0; ks < 2; ++ks)
          acc[mh * 2 + m][nh * BLO + n] = __builtin_amdgcn_mfma_f32_16x16x32_bf16(
              af[m][ks], bfr[nh][n][ks], acc[mh * 2 + m][nh * BLO + n], 0, 0, 0);
  };

  const int NT = K >> 6;
  stA(0, 0, 0); stB(0, 0, 0); stB(0, 1, 0); stA(0, 1, 0); stA(64, 0, 1);
  if constexpr (BN == 384) WAITV(5); else WAITV(4);
  __builtin_amdgcn_s_barrier();

  for (int kt = 0; kt < NT; ++kt) {
    const int b = kt & 1, nb = b ^ 1;
    const int k1 = ((kt + 1 < NT) ? kt + 1 : kt) << 6;
    const int k2 = ((kt + 2 < NT) ? kt + 2 : kt) << 6;
    // ---- phase 1: (mh0,nh0); stage B0(t+1) ----
    rdA(b, 0); rdB(b, 0);
    stB(k1, 0, nb);
    __builtin_amdgcn_s_setprio(1); mm(0, 0); __builtin_amdgcn_s_setprio(0);
    if constexpr (BN == 384) WAITV(5); else WAITV(4);  // drain B1(t)
    __builtin_amdgcn_s_barrier();
    // ---- phase 2: (mh0,nh1); stage B1(t+1) ----
    rdB(b, 1);
    stB(k1, 1, nb);
    __builtin_amdgcn_s_setprio(1); mm(0, 1); __builtin_amdgcn_s_setprio(0);
    if constexpr (BN == 384) WAITV(7); else WAITV(5);  // drain A1(t)
    __builtin_amdgcn_s_barrier();
    // ---- phase 3: (mh1,nh0); stage A1(t+1) ----
    rdA(b, 1);
    stA(k1, 1, nb);
    __builtin_amdgcn_s_setprio(1); mm(1, 0); __builtin_amdgcn_s_setprio(0);
    __builtin_amdgcn_s_barrier();
    // ---- phase 4: (mh1,nh1); stage A0(t+2) into buf b ----
    stA(k2, 0, b);
    __builtin_amdgcn_s_setprio(1); mm(1, 1); __builtin_amdgcn_s_setprio(0);
    if constexpr (BN == 384) WAITV(5); else WAITV(4);  // drain A0/B0(t+1)
    __builtin_amdgcn_s_barrier();
  }

  const int rb = m0 + wr * 64 + lg * 4;
  const int cb = n0 + wc * (BN / 4) + l16;
#pragma unroll
  for (int mi = 0; mi < 4; ++mi)
#pragma unroll
    for (int ni = 0; ni < 2 * BLO; ++ni)
#pragma unroll
      for (int r = 0; r < 4; ++r) {
        float v = acc[mi][ni][r];
        size_t idx2 = (size_t)(rb + mi * 16 + r) * N + cb + ni * 16;
        if constexpr (sizeof(TO) == 2) C[idx2] = f2bf(v);
        else C[idx2] = v;
      }
}

// -------- RoPE in-place on K ONLY (Q is rope'd in-register inside attn) -----
__global__ __launch_bounds__(256) void ropek_kernel(u16* __restrict__ qkv,
                                                    const float* __restrict__ cosT,
                                                    const float* __restrict__ sinT) {
  const int row = blockIdx.x * 2 + (threadIdx.x >> 7);  // b*S + s
  const int s = row & (S_LEN - 1);
  const int slot = threadIdx.x & 127;
  const int h = slot >> 3;
  const int c = slot & 7;
  u16* p = qkv + (size_t)row * QKVD + DIM + h * HD + c * 8;  // K part
  const float* cp = cosT + (s << 6) + c * 8;
  const float* sp = sinT + (s << 6) + c * 8;
  const float4 c0 = *(const float4*)cp, c1 = *(const float4*)(cp + 4);
  const float4 s0 = *(const float4*)sp, s1 = *(const float4*)(sp + 4);
  float cs[8] = {c0.x, c0.y, c0.z, c0.w, c1.x, c1.y, c1.z, c1.w};
  float sn[8] = {s0.x, s0.y, s0.z, s0.w, s1.x, s1.y, s1.z, s1.w};
  uint4 lo = *(const uint4*)p;
  uint4 hi = *(const uint4*)(p + 64);
  unsigned lw[4] = {lo.x, lo.y, lo.z, lo.w};
  unsigned hw[4] = {hi.x, hi.y, hi.z, hi.w};
  unsigned ol[4], oh[4];
#pragma unroll
  for (int j = 0; j < 4; ++j) {
    float x1a = bf2f((u16)(lw[j] & 0xffffu)), x1b = bf2f((u16)(lw[j] >> 16));
    float x2a = bf2f((u16)(hw[j] & 0xffffu)), x2b = bf2f((u16)(hw[j] >> 16));
    float ca = cs[j * 2], cb = cs[j * 2 + 1];
    float sa = sn[j * 2], sb = sn[j * 2 + 1];
    ol[j] = (u32)f2bf(x1a * ca - x2a * sa) | ((u32)f2bf(x1b * cb - x2b * sb) << 16);
    oh[j] = (u32)f2bf(x2a * ca + x1a * sa) | ((u32)f2bf(x2b * cb + x1b * sb) << 16);
  }
  *(uint4*)p = (uint4){ol[0], ol[1], ol[2], ol[3]};
  *(uint4*)(p + 64) = (uint4){oh[0], oh[1], oh[2], oh[3]};
}

// -------- sliding-window flash attention: QBLK=256, fragment reuse x2 ------
// grid = (B*H) * (S/256) = 256 blocks (1/CU). 8 waves x 32 q-rows (2 groups
// of 16). kf/vf LDS reads amortized over both groups.
__global__ __launch_bounds__(512, 1) void attn_kernel(const u16* __restrict__ qkv,
                                                      u16* __restrict__ attnO,
                                                      const float* __restrict__ cosT,
                                                      const float* __restrict__ sinT) {
  const int nwg = gridDim.x;  // 256
  const int wg = ((int)blockIdx.x & 7) * (nwg >> 3) + ((int)blockIdx.x >> 3);
  const int qt = wg & 7;     // 8 q-tiles of 256
  const int bh = wg >> 3;
  const int q0 = qt << 8;
  const int b = bh >> 4, h = bh & 15;
  const u16* Qp = qkv + (size_t)b * S_LEN * QKVD + h * HD;
  const u16* Kp = Qp + DIM;
  const u16* Vp = Qp + 2 * DIM;
  __shared__ __align__(16) char Ks[2][64 * 256];    // dbuf XOR-swizzled K
  __shared__ __align__(16) u16 Vt[128][72];         // transposed V, padded
  __shared__ __align__(16) u32 Ps[8][2][16 * 36];   // per-wave, per-group P
  const int t = threadIdx.x;
  const int w = t >> 6, l = t & 63;
  const int l16 = l & 15, lg = l >> 4;
  const int q0w = q0 + w * 32;  // wave owns 32 rows (2 groups of 16)
  const bf16x8 ones = __builtin_bit_cast(bf16x8,
      (uint4){0x3F803F80u, 0x3F803F80u, 0x3F803F80u, 0x3F803F80u});
  bf16x8 qf[2][4];
#pragma unroll
  for (int g = 0; g < 2; ++g) {
    const int srow = q0w + g * 16 + l16;
    const u16* qrow = Qp + (size_t)srow * QKVD;
#pragma unroll
    for (int ks = 0; ks < 4; ++ks) qf[g][ks] = *(const bf16x8*)(qrow + ks * 32 + lg * 8);
    // in-register RoPE on Q
    const float* cbase = cosT + (srow << 6) + lg * 8;
    const float* sbase = sinT + (srow << 6) + lg * 8;
#pragma unroll
    for (int ks = 0; ks < 2; ++ks) {
      const float4 ca = *(const float4*)(cbase + ks * 32);
      const float4 cb2 = *(const float4*)(cbase + ks * 32 + 4);
      const float4 sa = *(const float4*)(sbase + ks * 32);
      const float4 sb2 = *(const float4*)(sbase + ks * 32 + 4);
      const float cs[8] = {ca.x, ca.y, ca.z, ca.w, cb2.x, cb2.y, cb2.z, cb2.w};
      const float sn[8] = {sa.x, sa.y, sa.z, sa.w, sb2.x, sb2.y, sb2.z, sb2.w};
      const uint4 lv = __builtin_bit_cast(uint4, qf[g][ks]);
      const uint4 hv = __builtin_bit_cast(uint4, qf[g][ks + 2]);
      const unsigned li[4] = {lv.x, lv.y, lv.z, lv.w};
      const unsigned hi2[4] = {hv.x, hv.y, hv.z, hv.w};
      unsigned lw[4], hw[4];
#pragma unroll
      for (int p2 = 0; p2 < 4; ++p2) {
        float f1a = bf2f((u16)(li[p2] & 0xffffu)), f1b = bf2f((u16)(li[p2] >> 16));
        float f2a = bf2f((u16)(hi2[p2] & 0xffffu)), f2b = bf2f((u16)(hi2[p2] >> 16));
        lw[p2] = (u32)f2bf(f1a * cs[p2 * 2] - f2a * sn[p2 * 2]) |
                 ((u32)f2bf(f1b * cs[p2 * 2 + 1] - f2b * sn[p2 * 2 + 1]) << 16);
        hw[p2] = (u32)f2bf(f2a * cs[p2 * 2] + f1a * sn[p2 * 2]) |
                 ((u32)f2bf(f2b * cs[p2 * 2 + 1] + f1b * sn[p2 * 2 + 1]) << 16);
      }
      qf[g][ks] = __builtin_bit_cast(bf16x8, (uint4){lw[0], lw[1], lw[2], lw[3]});
      qf[g][ks + 2] = __builtin_bit_cast(bf16x8, (uint4){hw[0], hw[1], hw[2], hw[3]});
    }
  }
  f32x4 oacc[2][8] = {};
  f32x4 ldacc[2] = {};
  const int lo = max(0, (q0 - (WIN - 1)) >> 6);
  const int hi = (q0 + 255) >> 6;
  const int lo_w = max(0, (q0w - (WIN - 1)) >> 6);
  const int hi_w = (q0w + 31) >> 6;
  const float SC2 = 0.12751744654f;  // log2(e)/sqrt(128)
  const int dc = t & 15, pr_ = t >> 4;  // V-stage: d-chunk, kv-pair

  auto loadV = [&](int kv0, uint4& va, uint4& vb) {
    va = *(const uint4*)(Vp + (size_t)(kv0 + pr_ * 2) * QKVD + dc * 8);
    vb = *(const uint4*)(Vp + (size_t)(kv0 + pr_ * 2 + 1) * QKVD + dc * 8);
  };
  auto issueK = [&](int kv0, int buf) {
#pragma unroll
    for (int i = 0; i < 2; ++i) {
      int c = t + (i << 9);
      int row = c >> 4, ch = c & 15;
      int sch = ch ^ (row & 7);
      async16(Kp + (size_t)(kv0 + row) * QKVD + sch * 8, Ks[buf] + c * 16);
    }
  };

  uint4 va, vb, va2, vb2;
  loadV(lo << 6, va, vb);
  __builtin_amdgcn_sched_barrier(0);
  issueK(lo << 6, 0);
  __builtin_amdgcn_sched_barrier(0);

  for (int kt = lo; kt <= hi; ++kt) {
    const int buf = (kt - lo) & 1;
    const int kv0 = kt << 6;
    const int ktn = (kt < hi) ? kt + 1 : hi;
    WAITV(2);  // V(kt) regs ready; K(kt) still in flight
    __builtin_amdgcn_sched_barrier(0);
    __builtin_amdgcn_s_barrier();  // A: all waves done compute(kt-1)
    {
      const int kv = pr_ * 2, d0 = dc * 8;
      unsigned av[4] = {va.x, va.y, va.z, va.w};
      unsigned bv[4] = {vb.x, vb.y, vb.z, vb.w};
#pragma unroll
      for (int j = 0; j < 4; ++j) {
        *(unsigned*)&Vt[d0 + j * 2][kv] = (av[j] & 0xffffu) | (bv[j] << 16);
        *(unsigned*)&Vt[d0 + j * 2 + 1][kv] = (av[j] >> 16) | (bv[j] & 0xffff0000u);
      }
    }
    WAITV(0);  // K(kt) landed in Ks[buf]
    asm volatile("s_waitcnt lgkmcnt(0)" ::: "memory");
    __builtin_amdgcn_sched_barrier(0);
    __builtin_amdgcn_s_barrier();  // B: staging published
    loadV(ktn << 6, va2, vb2);
    __builtin_amdgcn_sched_barrier(0);
    issueK(ktn << 6, buf ^ 1);
    __builtin_amdgcn_sched_barrier(0);
    if (kt >= lo_w && kt <= hi_w) {
      // QK^T: kf read ONCE per (c4,ks), feeds both q-groups
#pragma unroll
      for (int c4 = 0; c4 < 4; ++c4) {
        f32x4 sa0 = {}, sa1 = {};
#pragma unroll
        for (int ks = 0; ks < 4; ++ks) {
          const int krow = c4 * 16 + l16;
          const int ch = (ks * 4 + lg) ^ (krow & 7);
          bf16x8 kf = *(const bf16x8*)(Ks[buf] + krow * 256 + ch * 16);
          sa0 = __builtin_amdgcn_mfma_f32_16x16x32_bf16(kf, qf[0][ks], sa0, 0, 0, 0);
          sa1 = __builtin_amdgcn_mfma_f32_16x16x32_bf16(kf, qf[1][ks], sa1, 0, 0, 0);
        }
        const int kj_base = kv0 + c4 * 16 + lg * 4;
#pragma unroll
        for (int g = 0; g < 2; ++g) {
          const f32x4 sa = g ? sa1 : sa0;
          const int qi = q0w + g * 16 + l16;
          float p[4];
#pragma unroll
          for (int r = 0; r < 4; ++r) {
            unsigned diff = (unsigned)(qi - (kj_base + r));
            float v = sa[r] * SC2;
            v = (diff < WIN) ? v : -1e30f;
            p[r] = __builtin_amdgcn_exp2f(v);
          }
          const u32 w0 = (u32)f2bf(p[0]) | ((u32)f2bf(p[1]) << 16);
          const u32 w1 = (u32)f2bf(p[2]) | ((u32)f2bf(p[3]) << 16);
          const int pw = l16 * 36 + c4 * 8 + lg * 2;
          Ps[w][g][pw] = w0;
          Ps[w][g][pw + 1] = w1;
        }
      }
      asm volatile("s_waitcnt lgkmcnt(0)" ::: "memory");
      __builtin_amdgcn_sched_barrier(0);
      // PV: vf read ONCE per (ks,dt), feeds both q-groups
#pragma unroll
      for (int ks = 0; ks < 2; ++ks) {
        uint4 p0 = *(const uint4*)&Ps[w][0][l16 * 36 + ks * 16 + lg * 4];
        uint4 p1 = *(const uint4*)&Ps[w][1][l16 * 36 + ks * 16 + lg * 4];
        bf16x8 pf0 = __builtin_bit_cast(bf16x8, p0);
        bf16x8 pf1 = __builtin_bit_cast(bf16x8, p1);
#pragma unroll
        for (int dt = 0; dt < 8; ++dt) {
          bf16x8 vf = *(const bf16x8*)(&Vt[dt * 16 + l16][ks * 32 + lg * 8]);
          oacc[0][dt] = __builtin_amdgcn_mfma_f32_16x16x32_bf16(pf0, vf, oacc[0][dt], 0, 0, 0);
          oacc[1][dt] = __builtin_amdgcn_mfma_f32_16x16x32_bf16(pf1, vf, oacc[1][dt], 0, 0, 0);
        }
        ldacc[0] = __builtin_amdgcn_mfma_f32_16x16x32_bf16(pf0, ones, ldacc[0], 0, 0, 0);
        ldacc[1] = __builtin_amdgcn_mfma_f32_16x16x32_bf16(pf1, ones, ldacc[1], 0, 0, 0);
      }
    }
    va = va2; vb = vb2;
  }
#pragma unroll
  for (int g = 0; g < 2; ++g) {
    const int qr = q0w + g * 16 + lg * 4;
    u16* orow = attnO + ((size_t)(b * S_LEN + qr) * DIM) + h * HD;
#pragma unroll
    for (int r = 0; r < 4; ++r) {
      float inv = 1.f / ldacc[g][r];
#pragma unroll
      for (int dt = 0; dt < 8; ++dt)
        orow[(size_t)r * DIM + dt * 16 + l16] = f2bf(oacc[g][dt][r] * inv);
    }
  }
}

extern "C" void kernel_launch(void* const* d_in, const int* in_sizes, int n_in,
                              void* d_out, int out_size, void* d_ws, size_t ws_size,
                              hipStream_t stream) {
  const float* x = (const float*)d_in[0];
  const float* w_qkv = (const float*)d_in[1];
  const float* w_out = (const float*)d_in[2];
  float* out = (float*)d_out;

  char* ws = (char*)d_ws;
  size_t off = 0;
  auto alloc = [&](size_t bytes) {
    void* p = ws + off;
    off = (off + bytes + 255) & ~(size_t)255;
    return p;
  };
  const size_t rows = 2ull * S_LEN;                // 4096
  u16* wqkvb = (u16*)alloc(3ull * DIM * DIM * 2);  // 25.2 MB (reused as attn out)
  u16* woutb = (u16*)alloc((size_t)DIM * DIM * 2); // 8.4 MB
  u16* xb    = (u16*)alloc(rows * DIM * 2);        // 16.8 MB
  u16* qkvb  = (u16*)alloc(rows * 3 * DIM * 2);    // 50.3 MB
  float* cosT = (float*)alloc((size_t)S_LEN * 64 * 4);
  float* sinT = (float*)alloc((size_t)S_LEN * 64 * 4);

  const int na = 3 * DIM * DIM, nb = DIM * DIM, nc = (int)(rows * DIM);
  const int nCvt = (na + nb + nc) / 1024;
  cvt3tab_kernel<<<nCvt + (S_LEN * 64) / 256, 256, 0, stream>>>(
      w_qkv, wqkvb, na, w_out, woutb, nb, x, xb, nc, cosT, sinT, nCvt);
  // QKV projection: 128x384, grid 512; XCD n-pinned B panels
  gemm8<384, u16><<<(int)(rows / 128) * (QKVD / 384), 512, 0, stream>>>(
      xb, wqkvb, qkvb, (int)rows, QKVD, DIM);
  // RoPE in-place on K only (Q rope'd inside attn)
  ropek_kernel<<<(int)(rows / 2), 256, 0, stream>>>(qkvb, cosT, sinT);
  // attention: QBLK=256, 256 blocks (1/CU), fragment reuse x2
  u16* attnb = wqkvb;
  attn_kernel<<<2 * NH * (S_LEN / 256), 512, 0, stream>>>(qkvb, attnb, cosT, sinT);
  // output projection: 128x256, grid 256 = 1 round; m-chunked
  gemm8<256, float><<<(int)(rows / 128) * (DIM / 256), 512, 0, stream>>>(
      attnb, woutb, out, (int)rows, DIM, DIM);
}